// Round 1
// baseline (470.119 us; speedup 1.0000x reference)
//
#include <hip/hip_runtime.h>
#include <stdint.h>

// Problem constants (reference: T=4096, H=2048, I=768, E=16, TOP_K=2)
#define T_TOK 4096
#define HDIM  2048
#define IDIM  768
#define NEXP  16
#define NPAIR (T_TOK * 2)        // 8192 (token, expert) pairs, exactly top-2
#define PAIR_CAP (NPAIR + 128)   // slack so padded tiles never read OOB

typedef float f32x4 __attribute__((ext_vector_type(4)));
typedef __bf16 bf16x8 __attribute__((ext_vector_type(8)));
typedef unsigned short u16x8 __attribute__((ext_vector_type(8)));
typedef unsigned int u32;
typedef const __attribute__((address_space(1))) u32* as1_u32p;
typedef __attribute__((address_space(3))) u32* as3_u32p;

__device__ __forceinline__ unsigned short f2bf(float f) {
  // fp32 -> bf16 round-to-nearest-even
  u32 u = __float_as_uint(f);
  u += 0x7FFFu + ((u >> 16) & 1u);
  return (unsigned short)(u >> 16);
}

__device__ __forceinline__ unsigned short tb(int m) {
  // 2-bit code m in {0,1,2} -> bf16 of {-1, 0, +1}
  return m == 0 ? (unsigned short)0xBF80 : (m == 2 ? (unsigned short)0x3F80 : (unsigned short)0);
}

__device__ __forceinline__ f32x4 mfma16(bf16x8 a, bf16x8 b, f32x4 c) {
  return __builtin_amdgcn_mfma_f32_16x16x32_bf16(a, b, c, 0, 0, 0);
}

// ---------------- routing ----------------
__global__ __launch_bounds__(256) void route_kernel(
    const float* __restrict__ logits, int* __restrict__ counts,
    int* __restrict__ t2i, float* __restrict__ t2w) {
  const int t = blockIdx.x * 256 + threadIdx.x;
  if (t >= T_TOK) return;
  const float* l = logits + t * NEXP;
  float m0 = -1e30f, m1 = -1e30f;
  int i0 = 0, i1 = 0;
#pragma unroll
  for (int j = 0; j < NEXP; ++j) {
    const float v = l[j];
    if (v > m0) { m1 = m0; i1 = i0; m0 = v; i0 = j; }
    else if (v > m1) { m1 = v; i1 = j; }
  }
  // renormalized top-2 softmax == softmax over the two top logits
  const float w0 = 1.0f / (1.0f + expf(m1 - m0));
  t2i[t] = i0 | (i1 << 8);
  t2w[t] = w0;
  atomicAdd(&counts[i0], 1);
  atomicAdd(&counts[i1], 1);
}

__global__ void scan_kernel(const int* __restrict__ counts,
                            int* __restrict__ offs, int* __restrict__ cursor) {
  if (threadIdx.x == 0) {
    int s = 0;
    for (int e = 0; e < NEXP; ++e) { offs[e] = s; cursor[e] = s; s += counts[e]; }
    offs[NEXP] = s;
  }
}

__global__ __launch_bounds__(256) void fill_kernel(
    const int* __restrict__ t2i, const float* __restrict__ t2w,
    int* __restrict__ cursor, int* __restrict__ pair_token,
    float* __restrict__ pair_wt) {
  const int t = blockIdx.x * 256 + threadIdx.x;
  if (t >= T_TOK) return;
  const int ii = t2i[t];
  const float w0 = t2w[t];
  const int i0 = ii & 255, i1 = (ii >> 8) & 255;
  const int p0 = atomicAdd(&cursor[i0], 1);
  pair_token[p0] = t; pair_wt[p0] = w0;
  const int p1 = atomicAdd(&cursor[i1], 1);
  pair_token[p1] = t; pair_wt[p1] = 1.0f - w0;
}

// ---------------- GEMM1: act'[pair, i] = silu(g)*u*a2, g/u = (x*a13) . tern13 ----------------
// Block tile: 128 pairs x (64 gate cols + 64 up cols), K = 2048, BK = 32.
// 4 waves, each wave = 32 rows x full 128 cols -> gate frag ni and up frag ni+4
// land in the SAME lane -> silu fusion entirely in-register.
__global__ __launch_bounds__(256) void gemm1_kernel(
    const float* __restrict__ x, const int* __restrict__ w13p,
    const int* __restrict__ a13q, const float* __restrict__ s13p,
    const int* __restrict__ a2q, const float* __restrict__ s2p,
    const int* __restrict__ counts, const int* __restrict__ offs,
    const int* __restrict__ pair_token, unsigned short* __restrict__ act) {
  const int nT = blockIdx.x;  // 0..11 : i-range nT*64..+63
  const int mT = blockIdx.y;  // 0..31 : pair tile (early exit)
  const int e  = blockIdx.z;
  const int cnt = counts[e];
  if (mT * 128 >= cnt) return;
  const int base = offs[e];
  const int tid = threadIdx.x;

  __shared__ float ald[HDIM];                 // a13[e, :] dequantized
  __shared__ unsigned short sA[128 * 40];     // pitch 40 (pad +8) keeps b128 conflicts <= 2-way
  __shared__ unsigned short sB[128 * 40];
  __shared__ int stok[128];

  const float s13 = *s13p;
  for (int h = tid; h < HDIM; h += 256) ald[h] = (float)a13q[e * HDIM + h] * s13;
  if (tid < 128) {
    const int m = mT * 128 + tid;
    stok[tid] = (m < cnt) ? pair_token[base + m] : 0;
  }
  __syncthreads();

  const int wave = tid >> 6, lane = tid & 63;
  const int quad = lane >> 4, ln = lane & 15;

  // A staging: 2 threads/row, 16 fp32 each
  const int ar = tid >> 1, akh = (tid & 1) << 4;
  const size_t xrow = (size_t)stok[ar] * HDIM;
  // B staging: 2 threads/row, 4 packed ints (16 weights) each
  const int bn = tid >> 1, bhalf = tid & 1;
  const int grow = (bn < 64) ? (nT * 64 + bn) : (IDIM + nT * 64 + (bn - 64));
  const int* bptr = w13p + ((size_t)e * (2 * IDIM) + grow) * (HDIM / 4) + bhalf * 4;
  unsigned short* sAw = sA + ar * 40 + akh;
  unsigned short* sBw = sB + bn * 40 + (bhalf << 4);

  f32x4 acc[2][8] = {};

  for (int kt = 0; kt < HDIM / 32; ++kt) {
    const int k0 = kt * 32;
    {  // stage A: bf16(x * alpha13)
      const float* xp = x + xrow + k0 + akh;
      const float* ap = ald + k0 + akh;
      const float4 f0 = ((const float4*)xp)[0];
      const float4 f1 = ((const float4*)xp)[1];
      const float4 f2 = ((const float4*)xp)[2];
      const float4 f3 = ((const float4*)xp)[3];
      u16x8 q0, q1;
      q0[0] = f2bf(f0.x * ap[0]);  q0[1] = f2bf(f0.y * ap[1]);
      q0[2] = f2bf(f0.z * ap[2]);  q0[3] = f2bf(f0.w * ap[3]);
      q0[4] = f2bf(f1.x * ap[4]);  q0[5] = f2bf(f1.y * ap[5]);
      q0[6] = f2bf(f1.z * ap[6]);  q0[7] = f2bf(f1.w * ap[7]);
      q1[0] = f2bf(f2.x * ap[8]);  q1[1] = f2bf(f2.y * ap[9]);
      q1[2] = f2bf(f2.z * ap[10]); q1[3] = f2bf(f2.w * ap[11]);
      q1[4] = f2bf(f3.x * ap[12]); q1[5] = f2bf(f3.y * ap[13]);
      q1[6] = f2bf(f3.z * ap[14]); q1[7] = f2bf(f3.w * ap[15]);
      *(u16x8*)(sAw) = q0;
      *(u16x8*)(sAw + 8) = q1;
    }
    {  // stage B: unpack 2-bit ternary -> bf16 {-1,0,1}
      const int4 wv = *(const int4*)(bptr + kt * 8);
      u16x8 q0, q1;
      q0[0] = tb(wv.x & 3); q0[1] = tb((wv.x >> 2) & 3); q0[2] = tb((wv.x >> 4) & 3); q0[3] = tb((wv.x >> 6) & 3);
      q0[4] = tb(wv.y & 3); q0[5] = tb((wv.y >> 2) & 3); q0[6] = tb((wv.y >> 4) & 3); q0[7] = tb((wv.y >> 6) & 3);
      q1[0] = tb(wv.z & 3); q1[1] = tb((wv.z >> 2) & 3); q1[2] = tb((wv.z >> 4) & 3); q1[3] = tb((wv.z >> 6) & 3);
      q1[4] = tb(wv.w & 3); q1[5] = tb((wv.w >> 2) & 3); q1[6] = tb((wv.w >> 4) & 3); q1[7] = tb((wv.w >> 6) & 3);
      *(u16x8*)(sBw) = q0;
      *(u16x8*)(sBw + 8) = q1;
    }
    __syncthreads();
    bf16x8 af[2];
#pragma unroll
    for (int mi = 0; mi < 2; ++mi)
      af[mi] = *(const bf16x8*)(sA + (wave * 32 + mi * 16 + ln) * 40 + quad * 8);
#pragma unroll
    for (int ni = 0; ni < 8; ++ni) {
      const bf16x8 bf = *(const bf16x8*)(sB + (ni * 16 + ln) * 40 + quad * 8);
      acc[0][ni] = mfma16(af[0], bf, acc[0][ni]);
      acc[1][ni] = mfma16(af[1], bf, acc[1][ni]);
    }
    __syncthreads();
  }

  // epilogue: act' = bf16(silu(gate) * up * a2[e,i])
  const float s2 = *s2p;
#pragma unroll
  for (int ni = 0; ni < 4; ++ni) {
    const int i = nT * 64 + ni * 16 + ln;
    const float a2v = (float)a2q[e * IDIM + i] * s2;
#pragma unroll
    for (int mi = 0; mi < 2; ++mi) {
      const f32x4 g = acc[mi][ni];
      const f32x4 u = acc[mi][ni + 4];
#pragma unroll
      for (int r = 0; r < 4; ++r) {
        const int m = mT * 128 + wave * 32 + mi * 16 + quad * 4 + r;
        if (m < cnt) {
          const float gv = g[r];
          const float av = gv / (1.0f + __expf(-gv)) * u[r];
          act[(size_t)(base + m) * IDIM + i] = f2bf(av * a2v);
        }
      }
    }
  }
}

// ---------------- GEMM2: out[t, h] += w * (act' . tern2) ----------------
// Block tile: 128 pairs x 128 h-cols, K = 768, BK = 32.
// A (act', bf16, linear) staged via global_load_lds width=16; B unpacked in regs.
__global__ __launch_bounds__(256) void gemm2_kernel(
    const int* __restrict__ w2p, const int* __restrict__ counts,
    const int* __restrict__ offs, const int* __restrict__ pair_token,
    const float* __restrict__ pair_wt, const unsigned short* __restrict__ act,
    float* __restrict__ out) {
  const int nT = blockIdx.x;  // 0..15 : h-range nT*128..+127
  const int mT = blockIdx.y;  // 0..31
  const int e  = blockIdx.z;
  const int cnt = counts[e];
  if (mT * 128 >= cnt) return;
  const int base = offs[e];
  const int tid = threadIdx.x;

  __shared__ unsigned short sA[128 * 32];  // unpadded: global_load_lds linear layout (m97 pattern)
  __shared__ unsigned short sB[128 * 40];
  __shared__ int stok[128];
  __shared__ float swt[128];

  if (tid < 128) {
    const int m = mT * 128 + tid;
    const bool v = m < cnt;
    stok[tid] = v ? pair_token[base + m] : 0;
    swt[tid]  = v ? pair_wt[base + m] : 0.0f;
  }

  const int wave = tid >> 6, lane = tid & 63;
  const int quad = lane >> 4, ln = lane & 15;

  const int bn = tid >> 1, bhalf = tid & 1;
  const int* bptr = w2p + ((size_t)e * HDIM + nT * 128 + bn) * (IDIM / 4) + bhalf * 4;
  unsigned short* sBw = sB + bn * 40 + (bhalf << 4);

  const int arow = lane >> 2;        // 16 rows per wave-call
  const int acol8 = (lane & 3) * 8;  // 8 bf16 = 16 B per lane
  const size_t arow0 = (size_t)(base + mT * 128);

  f32x4 acc[2][8] = {};

  for (int kt = 0; kt < IDIM / 32; ++kt) {
#pragma unroll
    for (int c = 0; c < 2; ++c) {  // each wave DMAs 2 x 16 rows of the A tile
      const int r = c * 64 + wave * 16 + arow;
      const unsigned short* gp = act + (arow0 + r) * IDIM + kt * 32 + acol8;
      unsigned short* lp = sA + (c * 64 + wave * 16) * 32;  // wave-uniform base
      __builtin_amdgcn_global_load_lds((as1_u32p)(const void*)gp, (as3_u32p)(void*)lp, 16, 0, 0);
    }
    {  // stage B
      const int4 wv = *(const int4*)(bptr + kt * 8);
      u16x8 q0, q1;
      q0[0] = tb(wv.x & 3); q0[1] = tb((wv.x >> 2) & 3); q0[2] = tb((wv.x >> 4) & 3); q0[3] = tb((wv.x >> 6) & 3);
      q0[4] = tb(wv.y & 3); q0[5] = tb((wv.y >> 2) & 3); q0[6] = tb((wv.y >> 4) & 3); q0[7] = tb((wv.y >> 6) & 3);
      q1[0] = tb(wv.z & 3); q1[1] = tb((wv.z >> 2) & 3); q1[2] = tb((wv.z >> 4) & 3); q1[3] = tb((wv.z >> 6) & 3);
      q1[4] = tb(wv.w & 3); q1[5] = tb((wv.w >> 2) & 3); q1[6] = tb((wv.w >> 4) & 3); q1[7] = tb((wv.w >> 6) & 3);
      *(u16x8*)(sBw) = q0;
      *(u16x8*)(sBw + 8) = q1;
    }
    __syncthreads();  // compiler drains vmcnt (global_load_lds) + lgkmcnt here
    bf16x8 af[2];
#pragma unroll
    for (int mi = 0; mi < 2; ++mi)
      af[mi] = *(const bf16x8*)(sA + (wave * 32 + mi * 16 + ln) * 32 + quad * 8);
#pragma unroll
    for (int ni = 0; ni < 8; ++ni) {
      const bf16x8 bf = *(const bf16x8*)(sB + (ni * 16 + ln) * 40 + quad * 8);
      acc[0][ni] = mfma16(af[0], bf, acc[0][ni]);
      acc[1][ni] = mfma16(af[1], bf, acc[1][ni]);
    }
    __syncthreads();
  }

  // epilogue: out[t, h] += w * down   (each out element receives exactly 2 adds)
#pragma unroll
  for (int mi = 0; mi < 2; ++mi) {
#pragma unroll
    for (int r = 0; r < 4; ++r) {
      const int ml = wave * 32 + mi * 16 + quad * 4 + r;
      const int m = mT * 128 + ml;
      if (m < cnt) {
        const float wgt = swt[ml];
        float* orow = out + (size_t)stok[ml] * HDIM + nT * 128;
#pragma unroll
        for (int ni = 0; ni < 8; ++ni)
          atomicAdd(orow + ni * 16 + ln, wgt * acc[mi][ni][r]);
      }
    }
  }
}

extern "C" void kernel_launch(void* const* d_in, const int* in_sizes, int n_in,
                              void* d_out, int out_size, void* d_ws, size_t ws_size,
                              hipStream_t stream) {
  const float* x      = (const float*)d_in[0];
  const float* logits = (const float*)d_in[1];
  const int*   w13p   = (const int*)d_in[2];   // harness widens uint8 -> int32
  const int*   a13q   = (const int*)d_in[3];   // int8 -> int32
  const float* s13    = (const float*)d_in[4];
  const int*   w2p    = (const int*)d_in[5];
  const int*   a2q    = (const int*)d_in[6];
  const float* s2     = (const float*)d_in[7];
  float* out = (float*)d_out;

  char* ws = (char*)d_ws;
  int*   counts     = (int*)(ws + 0);
  int*   cursor     = (int*)(ws + 64);
  int*   offs       = (int*)(ws + 128);
  int*   t2i        = (int*)(ws + 256);
  float* t2w        = (float*)(ws + 256 + 4 * T_TOK);
  int*   pair_token = (int*)(ws + 256 + 8 * T_TOK);
  float* pair_wt    = (float*)(ws + 256 + 8 * T_TOK + 4 * PAIR_CAP);
  unsigned short* act = (unsigned short*)(ws + 256 + 8 * T_TOK + 8 * PAIR_CAP);
  // total ws use: 256 + 32 KB + 65 KB + 12.8 MB  (~12.9 MB)

  hipMemsetAsync(counts, 0, 256, stream);                          // counts/cursor/offs
  hipMemsetAsync(out, 0, (size_t)out_size * sizeof(float), stream);

  route_kernel<<<T_TOK / 256, 256, 0, stream>>>(logits, counts, t2i, t2w);
  scan_kernel<<<1, 64, 0, stream>>>(counts, offs, cursor);
  fill_kernel<<<T_TOK / 256, 256, 0, stream>>>(t2i, t2w, cursor, pair_token, pair_wt);
  gemm1_kernel<<<dim3(12, 32, 16), 256, 0, stream>>>(x, w13p, a13q, s13, a2q, s2,
                                                     counts, offs, pair_token, act);
  gemm2_kernel<<<dim3(16, 32, 16), 256, 0, stream>>>(w2p, counts, offs, pair_token,
                                                     pair_wt, act, out);
}

// Round 2
// 395.300 us; speedup vs baseline: 1.1893x; 1.1893x over previous
//
#include <hip/hip_runtime.h>
#include <stdint.h>

// Problem constants (reference: T=4096, H=2048, I=768, E=16, TOP_K=2)
#define T_TOK 4096
#define HDIM  2048
#define IDIM  768
#define NEXP  16
#define NPAIR (T_TOK * 2)          // 8192 (token, expert) pairs, exactly top-2
#define PAIR_CAP_FB (NPAIR + 128)  // fallback (M=128) padded row bound
#define PAIR_CAP    (NPAIR + 256)  // new path (M=256): rows touched <= offs[e+1]+255 <= 8447

typedef float f32x4 __attribute__((ext_vector_type(4)));
typedef __bf16 bf16x8 __attribute__((ext_vector_type(8)));
typedef unsigned short u16x8 __attribute__((ext_vector_type(8)));
typedef unsigned int u32;
typedef const __attribute__((address_space(1))) u32* as1_u32p;
typedef __attribute__((address_space(3))) u32* as3_u32p;

__device__ __forceinline__ unsigned short f2bf(float f) {
  // fp32 -> bf16 round-to-nearest-even
  u32 u = __float_as_uint(f);
  u += 0x7FFFu + ((u >> 16) & 1u);
  return (unsigned short)(u >> 16);
}

__device__ __forceinline__ unsigned short tb(int m) {
  // 2-bit code m in {0,1,2} -> bf16 of {-1, 0, +1}
  return m == 0 ? (unsigned short)0xBF80 : (m == 2 ? (unsigned short)0x3F80 : (unsigned short)0);
}

__device__ __forceinline__ f32x4 mfma16(bf16x8 a, bf16x8 b, f32x4 c) {
  return __builtin_amdgcn_mfma_f32_16x16x32_bf16(a, b, c, 0, 0, 0);
}

// ---------------- routing ----------------
__global__ __launch_bounds__(256) void route_kernel(
    const float* __restrict__ logits, int* __restrict__ counts,
    int* __restrict__ t2i, float* __restrict__ t2w) {
  const int t = blockIdx.x * 256 + threadIdx.x;
  if (t >= T_TOK) return;
  const float* l = logits + t * NEXP;
  float m0 = -1e30f, m1 = -1e30f;
  int i0 = 0, i1 = 0;
#pragma unroll
  for (int j = 0; j < NEXP; ++j) {
    const float v = l[j];
    if (v > m0) { m1 = m0; i1 = i0; m0 = v; i0 = j; }
    else if (v > m1) { m1 = v; i1 = j; }
  }
  // renormalized top-2 softmax == softmax over the two top logits
  const float w0 = 1.0f / (1.0f + expf(m1 - m0));
  t2i[t] = i0 | (i1 << 8);
  t2w[t] = w0;
  atomicAdd(&counts[i0], 1);
  atomicAdd(&counts[i1], 1);
}

__global__ void scan_kernel(const int* __restrict__ counts,
                            int* __restrict__ offs, int* __restrict__ cursor) {
  if (threadIdx.x == 0) {
    int s = 0;
    for (int e = 0; e < NEXP; ++e) { offs[e] = s; cursor[e] = s; s += counts[e]; }
    offs[NEXP] = s;
  }
}

__global__ __launch_bounds__(256) void fill_kernel(
    const int* __restrict__ t2i, const float* __restrict__ t2w,
    int* __restrict__ cursor, int* __restrict__ pair_token,
    float* __restrict__ pair_wt, int* __restrict__ pair_eid) {
  const int t = blockIdx.x * 256 + threadIdx.x;
  if (t >= T_TOK) return;
  const int ii = t2i[t];
  const float w0 = t2w[t];
  const int i0 = ii & 255, i1 = (ii >> 8) & 255;
  const int p0 = atomicAdd(&cursor[i0], 1);
  pair_token[p0] = t; pair_wt[p0] = w0; pair_eid[p0] = i0;
  const int p1 = atomicAdd(&cursor[i1], 1);
  pair_token[p1] = t; pair_wt[p1] = 1.0f - w0; pair_eid[p1] = i1;
}

// ---------------- xg prepass: xg[p,h] = bf16(x[tok(p),h] * a13[e(p),h]) ----------------
// One block per pair row; done ONCE instead of 12x inside gemm1's nT blocks.
__global__ __launch_bounds__(256) void xg_kernel(
    const float* __restrict__ x, const int* __restrict__ a13q,
    const float* __restrict__ s13p, const int* __restrict__ pair_token,
    const int* __restrict__ pair_eid, unsigned short* __restrict__ xg) {
  const int p = blockIdx.x;
  const int t = pair_token[p];
  const int e = pair_eid[p];
  const float s13 = *s13p;
  const int h0 = threadIdx.x * 8;  // 256 threads x 8 elems = 2048
  const float* xp = x + (size_t)t * HDIM + h0;
  const int* ap = a13q + (size_t)e * HDIM + h0;
  const float4 x0 = ((const float4*)xp)[0];
  const float4 x1 = ((const float4*)xp)[1];
  const int4 a0 = ((const int4*)ap)[0];
  const int4 a1 = ((const int4*)ap)[1];
  u16x8 q;
  q[0] = f2bf(x0.x * (float)a0.x * s13);
  q[1] = f2bf(x0.y * (float)a0.y * s13);
  q[2] = f2bf(x0.z * (float)a0.z * s13);
  q[3] = f2bf(x0.w * (float)a0.w * s13);
  q[4] = f2bf(x1.x * (float)a1.x * s13);
  q[5] = f2bf(x1.y * (float)a1.y * s13);
  q[6] = f2bf(x1.z * (float)a1.z * s13);
  q[7] = f2bf(x1.w * (float)a1.w * s13);
  *(u16x8*)(xg + (size_t)p * HDIM + h0) = q;
}

// ---------------- GEMM1 (new): act'[pair,i] = silu(g)*u*a2 ----------------
// Block: 256 pairs x (64 gate + 64 up cols), K=2048, BK=32. A via global_load_lds
// (xg is linear bf16), B via 2KB LDS LUT (byte -> 4 bf16). acc[4][8], 4 waves
// each covering 64 rows x 128 cols -> gate frag ni and up frag ni+4 same lane.
__global__ __launch_bounds__(256, 2) void gemm1_kernel(
    const int* __restrict__ w13p, const int* __restrict__ a2q,
    const float* __restrict__ s2p, const int* __restrict__ counts,
    const int* __restrict__ offs, const unsigned short* __restrict__ xg,
    unsigned short* __restrict__ act) {
  const int nT = blockIdx.x;  // 0..11 : i-range nT*64..+63
  const int mT = blockIdx.y;  // 0..15 : pair tile (early exit)
  const int e  = blockIdx.z;
  const int cnt = counts[e];
  if (mT * 256 >= cnt) return;
  const int base = offs[e];
  const int tid = threadIdx.x;

  __shared__ unsigned short sA[256 * 32];  // unpadded: global_load_lds layout
  __shared__ unsigned short sB[128 * 40];  // pitch 40 pad
  __shared__ uint2 lut[256];               // byte -> 4 bf16 ternary values

  {  // LUT init (once per block)
    const int b = tid;
    const u32 lo = (u32)tb(b & 3) | ((u32)tb((b >> 2) & 3) << 16);
    const u32 hi = (u32)tb((b >> 4) & 3) | ((u32)tb((b >> 6) & 3) << 16);
    lut[b] = make_uint2(lo, hi);
  }
  __syncthreads();

  const int wave = tid >> 6, lane = tid & 63;
  const int quad = lane >> 4, ln = lane & 15;

  // B staging: 2 threads/row, 16 codes (4 widened bytes) each
  const int bn = tid >> 1, bhalf = tid & 1;
  const int grow = (bn < 64) ? (nT * 64 + bn) : (IDIM + nT * 64 + (bn - 64));
  const int* bptr = w13p + ((size_t)e * (2 * IDIM) + grow) * (HDIM / 4) + bhalf * 4;
  unsigned short* sBw = sB + bn * 40 + (bhalf << 4);

  // A DMA lane addressing: 16 rows x 32 cols per instruction
  const int arow = lane >> 2;
  const int acol = (lane & 3) * 8;
  const size_t arow0 = (size_t)(base + mT * 256);

  f32x4 acc[4][8] = {};

  for (int kt = 0; kt < HDIM / 32; ++kt) {
#pragma unroll
    for (int c = 0; c < 4; ++c) {  // each wave DMAs 4 x 16 rows
      const unsigned short* gp =
          xg + (arow0 + c * 64 + wave * 16 + arow) * HDIM + kt * 32 + acol;
      unsigned short* lp = sA + (c * 64 + wave * 16) * 32;  // wave-uniform base
      __builtin_amdgcn_global_load_lds((as1_u32p)(const void*)gp, (as3_u32p)(void*)lp, 16, 0, 0);
    }
    {  // stage B via LUT
      const int4 wv = *(const int4*)(bptr + kt * 8);
      const uint2 q0 = lut[wv.x], q1 = lut[wv.y], q2 = lut[wv.z], q3 = lut[wv.w];
      *(uint2*)(sBw + 0) = q0;
      *(uint2*)(sBw + 4) = q1;
      *(uint2*)(sBw + 8) = q2;
      *(uint2*)(sBw + 12) = q3;
    }
    __syncthreads();
    bf16x8 af[4];
#pragma unroll
    for (int mi = 0; mi < 4; ++mi)
      af[mi] = *(const bf16x8*)(sA + (wave * 64 + mi * 16 + ln) * 32 + quad * 8);
#pragma unroll
    for (int ni = 0; ni < 8; ++ni) {
      const bf16x8 bf = *(const bf16x8*)(sB + (ni * 16 + ln) * 40 + quad * 8);
#pragma unroll
      for (int mi = 0; mi < 4; ++mi) acc[mi][ni] = mfma16(af[mi], bf, acc[mi][ni]);
    }
    __syncthreads();
  }

  // epilogue: act' = bf16(silu(gate) * up * a2[e,i])
  const float s2 = *s2p;
#pragma unroll
  for (int ni = 0; ni < 4; ++ni) {
    const int i = nT * 64 + ni * 16 + ln;
    const float a2v = (float)a2q[e * IDIM + i] * s2;
#pragma unroll
    for (int mi = 0; mi < 4; ++mi) {
      const f32x4 g = acc[mi][ni];
      const f32x4 u = acc[mi][ni + 4];
#pragma unroll
      for (int r = 0; r < 4; ++r) {
        const int m = mT * 256 + wave * 64 + mi * 16 + quad * 4 + r;
        if (m < cnt) {
          const float gv = g[r];
          const float av = gv / (1.0f + __expf(-gv)) * u[r];
          act[(size_t)(base + m) * IDIM + i] = f2bf(av * a2v);
        }
      }
    }
  }
}

// ---------------- GEMM2 (new): out[t,h] += w * (act' . tern2) ----------------
// Block: 256 pairs x 128 h-cols, K=768, BK=32. A DMA'd, B via LUT.
__global__ __launch_bounds__(256, 2) void gemm2_kernel(
    const int* __restrict__ w2p, const int* __restrict__ counts,
    const int* __restrict__ offs, const int* __restrict__ pair_token,
    const float* __restrict__ pair_wt, const unsigned short* __restrict__ act,
    float* __restrict__ out) {
  const int nT = blockIdx.x;  // 0..15 : h-range nT*128..+127
  const int mT = blockIdx.y;  // 0..15
  const int e  = blockIdx.z;
  const int cnt = counts[e];
  if (mT * 256 >= cnt) return;
  const int base = offs[e];
  const int tid = threadIdx.x;

  __shared__ unsigned short sA[256 * 32];
  __shared__ unsigned short sB[128 * 40];
  __shared__ uint2 lut[256];
  __shared__ int stok[256];
  __shared__ float swt[256];

  {
    const int b = tid;
    const u32 lo = (u32)tb(b & 3) | ((u32)tb((b >> 2) & 3) << 16);
    const u32 hi = (u32)tb((b >> 4) & 3) | ((u32)tb((b >> 6) & 3) << 16);
    lut[b] = make_uint2(lo, hi);
    const int m = mT * 256 + tid;
    const bool v = m < cnt;
    stok[tid] = v ? pair_token[base + m] : 0;
    swt[tid]  = v ? pair_wt[base + m] : 0.0f;
  }
  __syncthreads();

  const int wave = tid >> 6, lane = tid & 63;
  const int quad = lane >> 4, ln = lane & 15;

  const int bn = tid >> 1, bhalf = tid & 1;
  const int* bptr = w2p + ((size_t)e * HDIM + nT * 128 + bn) * (IDIM / 4) + bhalf * 4;
  unsigned short* sBw = sB + bn * 40 + (bhalf << 4);

  const int arow = lane >> 2;
  const int acol = (lane & 3) * 8;
  const size_t arow0 = (size_t)(base + mT * 256);

  f32x4 acc[4][8] = {};

  for (int kt = 0; kt < IDIM / 32; ++kt) {
#pragma unroll
    for (int c = 0; c < 4; ++c) {
      const unsigned short* gp =
          act + (arow0 + c * 64 + wave * 16 + arow) * IDIM + kt * 32 + acol;
      unsigned short* lp = sA + (c * 64 + wave * 16) * 32;
      __builtin_amdgcn_global_load_lds((as1_u32p)(const void*)gp, (as3_u32p)(void*)lp, 16, 0, 0);
    }
    {
      const int4 wv = *(const int4*)(bptr + kt * 8);
      const uint2 q0 = lut[wv.x], q1 = lut[wv.y], q2 = lut[wv.z], q3 = lut[wv.w];
      *(uint2*)(sBw + 0) = q0;
      *(uint2*)(sBw + 4) = q1;
      *(uint2*)(sBw + 8) = q2;
      *(uint2*)(sBw + 12) = q3;
    }
    __syncthreads();
    bf16x8 af[4];
#pragma unroll
    for (int mi = 0; mi < 4; ++mi)
      af[mi] = *(const bf16x8*)(sA + (wave * 64 + mi * 16 + ln) * 32 + quad * 8);
#pragma unroll
    for (int ni = 0; ni < 8; ++ni) {
      const bf16x8 bf = *(const bf16x8*)(sB + (ni * 16 + ln) * 40 + quad * 8);
#pragma unroll
      for (int mi = 0; mi < 4; ++mi) acc[mi][ni] = mfma16(af[mi], bf, acc[mi][ni]);
    }
    __syncthreads();
  }

  // epilogue: out[t,h] += w * down (each element receives exactly 2 adds)
#pragma unroll
  for (int mi = 0; mi < 4; ++mi) {
#pragma unroll
    for (int r = 0; r < 4; ++r) {
      const int ml = wave * 64 + mi * 16 + quad * 4 + r;
      const int m = mT * 256 + ml;
      if (m < cnt) {
        const float wgt = swt[ml];
        float* orow = out + (size_t)stok[ml] * HDIM + nT * 128;
#pragma unroll
        for (int ni = 0; ni < 8; ++ni)
          atomicAdd(orow + ni * 16 + ln, wgt * acc[mi][ni][r]);
      }
    }
  }
}

// ================= FALLBACK path (Round-1 kernels, used if ws too small) =================
__global__ __launch_bounds__(256) void gemm1_fb(
    const float* __restrict__ x, const int* __restrict__ w13p,
    const int* __restrict__ a13q, const float* __restrict__ s13p,
    const int* __restrict__ a2q, const float* __restrict__ s2p,
    const int* __restrict__ counts, const int* __restrict__ offs,
    const int* __restrict__ pair_token, unsigned short* __restrict__ act) {
  const int nT = blockIdx.x;
  const int mT = blockIdx.y;
  const int e  = blockIdx.z;
  const int cnt = counts[e];
  if (mT * 128 >= cnt) return;
  const int base = offs[e];
  const int tid = threadIdx.x;

  __shared__ float ald[HDIM];
  __shared__ unsigned short sA[128 * 40];
  __shared__ unsigned short sB[128 * 40];
  __shared__ int stok[128];

  const float s13 = *s13p;
  for (int h = tid; h < HDIM; h += 256) ald[h] = (float)a13q[e * HDIM + h] * s13;
  if (tid < 128) {
    const int m = mT * 128 + tid;
    stok[tid] = (m < cnt) ? pair_token[base + m] : 0;
  }
  __syncthreads();

  const int wave = tid >> 6, lane = tid & 63;
  const int quad = lane >> 4, ln = lane & 15;

  const int ar = tid >> 1, akh = (tid & 1) << 4;
  const size_t xrow = (size_t)stok[ar] * HDIM;
  const int bn = tid >> 1, bhalf = tid & 1;
  const int grow = (bn < 64) ? (nT * 64 + bn) : (IDIM + nT * 64 + (bn - 64));
  const int* bptr = w13p + ((size_t)e * (2 * IDIM) + grow) * (HDIM / 4) + bhalf * 4;
  unsigned short* sAw = sA + ar * 40 + akh;
  unsigned short* sBw = sB + bn * 40 + (bhalf << 4);

  f32x4 acc[2][8] = {};

  for (int kt = 0; kt < HDIM / 32; ++kt) {
    const int k0 = kt * 32;
    {
      const float* xp = x + xrow + k0 + akh;
      const float* ap = ald + k0 + akh;
      const float4 f0 = ((const float4*)xp)[0];
      const float4 f1 = ((const float4*)xp)[1];
      const float4 f2 = ((const float4*)xp)[2];
      const float4 f3 = ((const float4*)xp)[3];
      u16x8 q0, q1;
      q0[0] = f2bf(f0.x * ap[0]);  q0[1] = f2bf(f0.y * ap[1]);
      q0[2] = f2bf(f0.z * ap[2]);  q0[3] = f2bf(f0.w * ap[3]);
      q0[4] = f2bf(f1.x * ap[4]);  q0[5] = f2bf(f1.y * ap[5]);
      q0[6] = f2bf(f1.z * ap[6]);  q0[7] = f2bf(f1.w * ap[7]);
      q1[0] = f2bf(f2.x * ap[8]);  q1[1] = f2bf(f2.y * ap[9]);
      q1[2] = f2bf(f2.z * ap[10]); q1[3] = f2bf(f2.w * ap[11]);
      q1[4] = f2bf(f3.x * ap[12]); q1[5] = f2bf(f3.y * ap[13]);
      q1[6] = f2bf(f3.z * ap[14]); q1[7] = f2bf(f3.w * ap[15]);
      *(u16x8*)(sAw) = q0;
      *(u16x8*)(sAw + 8) = q1;
    }
    {
      const int4 wv = *(const int4*)(bptr + kt * 8);
      u16x8 q0, q1;
      q0[0] = tb(wv.x & 3); q0[1] = tb((wv.x >> 2) & 3); q0[2] = tb((wv.x >> 4) & 3); q0[3] = tb((wv.x >> 6) & 3);
      q0[4] = tb(wv.y & 3); q0[5] = tb((wv.y >> 2) & 3); q0[6] = tb((wv.y >> 4) & 3); q0[7] = tb((wv.y >> 6) & 3);
      q1[0] = tb(wv.z & 3); q1[1] = tb((wv.z >> 2) & 3); q1[2] = tb((wv.z >> 4) & 3); q1[3] = tb((wv.z >> 6) & 3);
      q1[4] = tb(wv.w & 3); q1[5] = tb((wv.w >> 2) & 3); q1[6] = tb((wv.w >> 4) & 3); q1[7] = tb((wv.w >> 6) & 3);
      *(u16x8*)(sBw) = q0;
      *(u16x8*)(sBw + 8) = q1;
    }
    __syncthreads();
    bf16x8 af[2];
#pragma unroll
    for (int mi = 0; mi < 2; ++mi)
      af[mi] = *(const bf16x8*)(sA + (wave * 32 + mi * 16 + ln) * 40 + quad * 8);
#pragma unroll
    for (int ni = 0; ni < 8; ++ni) {
      const bf16x8 bf = *(const bf16x8*)(sB + (ni * 16 + ln) * 40 + quad * 8);
      acc[0][ni] = mfma16(af[0], bf, acc[0][ni]);
      acc[1][ni] = mfma16(af[1], bf, acc[1][ni]);
    }
    __syncthreads();
  }

  const float s2 = *s2p;
#pragma unroll
  for (int ni = 0; ni < 4; ++ni) {
    const int i = nT * 64 + ni * 16 + ln;
    const float a2v = (float)a2q[e * IDIM + i] * s2;
#pragma unroll
    for (int mi = 0; mi < 2; ++mi) {
      const f32x4 g = acc[mi][ni];
      const f32x4 u = acc[mi][ni + 4];
#pragma unroll
      for (int r = 0; r < 4; ++r) {
        const int m = mT * 128 + wave * 32 + mi * 16 + quad * 4 + r;
        if (m < cnt) {
          const float gv = g[r];
          const float av = gv / (1.0f + __expf(-gv)) * u[r];
          act[(size_t)(base + m) * IDIM + i] = f2bf(av * a2v);
        }
      }
    }
  }
}

__global__ __launch_bounds__(256) void gemm2_fb(
    const int* __restrict__ w2p, const int* __restrict__ counts,
    const int* __restrict__ offs, const int* __restrict__ pair_token,
    const float* __restrict__ pair_wt, const unsigned short* __restrict__ act,
    float* __restrict__ out) {
  const int nT = blockIdx.x;
  const int mT = blockIdx.y;
  const int e  = blockIdx.z;
  const int cnt = counts[e];
  if (mT * 128 >= cnt) return;
  const int base = offs[e];
  const int tid = threadIdx.x;

  __shared__ unsigned short sA[128 * 32];
  __shared__ unsigned short sB[128 * 40];
  __shared__ int stok[128];
  __shared__ float swt[128];

  if (tid < 128) {
    const int m = mT * 128 + tid;
    const bool v = m < cnt;
    stok[tid] = v ? pair_token[base + m] : 0;
    swt[tid]  = v ? pair_wt[base + m] : 0.0f;
  }

  const int wave = tid >> 6, lane = tid & 63;
  const int quad = lane >> 4, ln = lane & 15;

  const int bn = tid >> 1, bhalf = tid & 1;
  const int* bptr = w2p + ((size_t)e * HDIM + nT * 128 + bn) * (IDIM / 4) + bhalf * 4;
  unsigned short* sBw = sB + bn * 40 + (bhalf << 4);

  const int arow = lane >> 2;
  const int acol8 = (lane & 3) * 8;
  const size_t arow0 = (size_t)(base + mT * 128);

  f32x4 acc[2][8] = {};

  for (int kt = 0; kt < IDIM / 32; ++kt) {
#pragma unroll
    for (int c = 0; c < 2; ++c) {
      const int r = c * 64 + wave * 16 + arow;
      const unsigned short* gp = act + (arow0 + r) * IDIM + kt * 32 + acol8;
      unsigned short* lp = sA + (c * 64 + wave * 16) * 32;
      __builtin_amdgcn_global_load_lds((as1_u32p)(const void*)gp, (as3_u32p)(void*)lp, 16, 0, 0);
    }
    {
      const int4 wv = *(const int4*)(bptr + kt * 8);
      u16x8 q0, q1;
      q0[0] = tb(wv.x & 3); q0[1] = tb((wv.x >> 2) & 3); q0[2] = tb((wv.x >> 4) & 3); q0[3] = tb((wv.x >> 6) & 3);
      q0[4] = tb(wv.y & 3); q0[5] = tb((wv.y >> 2) & 3); q0[6] = tb((wv.y >> 4) & 3); q0[7] = tb((wv.y >> 6) & 3);
      q1[0] = tb(wv.z & 3); q1[1] = tb((wv.z >> 2) & 3); q1[2] = tb((wv.z >> 4) & 3); q1[3] = tb((wv.z >> 6) & 3);
      q1[4] = tb(wv.w & 3); q1[5] = tb((wv.w >> 2) & 3); q1[6] = tb((wv.w >> 4) & 3); q1[7] = tb((wv.w >> 6) & 3);
      *(u16x8*)(sBw) = q0;
      *(u16x8*)(sBw + 8) = q1;
    }
    __syncthreads();
    bf16x8 af[2];
#pragma unroll
    for (int mi = 0; mi < 2; ++mi)
      af[mi] = *(const bf16x8*)(sA + (wave * 32 + mi * 16 + ln) * 32 + quad * 8);
#pragma unroll
    for (int ni = 0; ni < 8; ++ni) {
      const bf16x8 bf = *(const bf16x8*)(sB + (ni * 16 + ln) * 40 + quad * 8);
      acc[0][ni] = mfma16(af[0], bf, acc[0][ni]);
      acc[1][ni] = mfma16(af[1], bf, acc[1][ni]);
    }
    __syncthreads();
  }

#pragma unroll
  for (int mi = 0; mi < 2; ++mi) {
#pragma unroll
    for (int r = 0; r < 4; ++r) {
      const int ml = wave * 32 + mi * 16 + quad * 4 + r;
      const int m = mT * 128 + ml;
      if (m < cnt) {
        const float wgt = swt[ml];
        float* orow = out + (size_t)stok[ml] * HDIM + nT * 128;
#pragma unroll
        for (int ni = 0; ni < 8; ++ni)
          atomicAdd(orow + ni * 16 + ln, wgt * acc[mi][ni][r]);
      }
    }
  }
}

extern "C" void kernel_launch(void* const* d_in, const int* in_sizes, int n_in,
                              void* d_out, int out_size, void* d_ws, size_t ws_size,
                              hipStream_t stream) {
  const float* x      = (const float*)d_in[0];
  const float* logits = (const float*)d_in[1];
  const int*   w13p   = (const int*)d_in[2];   // harness widens uint8 -> int32
  const int*   a13q   = (const int*)d_in[3];   // int8 -> int32
  const float* s13    = (const float*)d_in[4];
  const int*   w2p    = (const int*)d_in[5];
  const int*   a2q    = (const int*)d_in[6];
  const float* s2     = (const float*)d_in[7];
  float* out = (float*)d_out;

  // ---- unified header layout ----
  char* ws = (char*)d_ws;
  int*   counts     = (int*)(ws + 0);
  int*   cursor     = (int*)(ws + 64);
  int*   offs       = (int*)(ws + 128);
  int*   t2i        = (int*)(ws + 256);
  float* t2w        = (float*)(ws + 256 + 4 * T_TOK);
  int*   pair_token = (int*)(ws + 256 + 8 * T_TOK);
  float* pair_wt    = (float*)(ws + 256 + 8 * T_TOK + 4 * PAIR_CAP);
  int*   pair_eid   = (int*)(ws + 256 + 8 * T_TOK + 8 * PAIR_CAP);
  const size_t hdr_end = ((size_t)(256 + 8 * T_TOK + 12 * PAIR_CAP) + 255) & ~(size_t)255;

  const size_t xg_bytes  = (size_t)PAIR_CAP * HDIM * 2;   // ~34.6 MB
  const size_t act_bytes = (size_t)PAIR_CAP * IDIM * 2;   // ~13.0 MB
  const size_t need_new = hdr_end + xg_bytes + act_bytes; // ~47.8 MB

  hipMemsetAsync(counts, 0, 256, stream);
  hipMemsetAsync(out, 0, (size_t)out_size * sizeof(float), stream);

  route_kernel<<<T_TOK / 256, 256, 0, stream>>>(logits, counts, t2i, t2w);
  scan_kernel<<<1, 64, 0, stream>>>(counts, offs, cursor);
  fill_kernel<<<T_TOK / 256, 256, 0, stream>>>(t2i, t2w, cursor, pair_token, pair_wt, pair_eid);

  if (ws_size >= need_new) {
    unsigned short* xg  = (unsigned short*)(ws + hdr_end);
    unsigned short* act = (unsigned short*)(ws + hdr_end + xg_bytes);
    xg_kernel<<<NPAIR, 256, 0, stream>>>(x, a13q, s13, pair_token, pair_eid, xg);
    gemm1_kernel<<<dim3(12, 16, 16), 256, 0, stream>>>(w13p, a2q, s2, counts, offs, xg, act);
    gemm2_kernel<<<dim3(16, 16, 16), 256, 0, stream>>>(w2p, counts, offs, pair_token,
                                                       pair_wt, act, out);
  } else {
    unsigned short* act = (unsigned short*)(ws + hdr_end);
    gemm1_fb<<<dim3(12, 32, 16), 256, 0, stream>>>(x, w13p, a13q, s13, a2q, s2,
                                                   counts, offs, pair_token, act);
    gemm2_fb<<<dim3(16, 32, 16), 256, 0, stream>>>(w2p, counts, offs, pair_token,
                                                   pair_wt, act, out);
  }
}

// Round 3
// 390.581 us; speedup vs baseline: 1.2036x; 1.0121x over previous
//
#include <hip/hip_runtime.h>
#include <stdint.h>

// Problem constants (reference: T=4096, H=2048, I=768, E=16, TOP_K=2)
#define T_TOK 4096
#define HDIM  2048
#define IDIM  768
#define NEXP  16
#define NPAIR (T_TOK * 2)        // 8192 (token, expert) pairs, exactly top-2
#define PAIR_CAP (NPAIR + 256)   // padded row bound for DMA reads past segment end

typedef float f32x4 __attribute__((ext_vector_type(4)));
typedef __bf16 bf16x8 __attribute__((ext_vector_type(8)));
typedef unsigned short u16x8 __attribute__((ext_vector_type(8)));
typedef unsigned int u32;
typedef const __attribute__((address_space(1))) u32* as1_u32p;
typedef __attribute__((address_space(3))) u32* as3_u32p;

__device__ __forceinline__ unsigned short f2bf(float f) {
  u32 u = __float_as_uint(f);
  u += 0x7FFFu + ((u >> 16) & 1u);
  return (unsigned short)(u >> 16);
}

__device__ __forceinline__ unsigned short tb(int m) {
  return m == 0 ? (unsigned short)0xBF80 : (m == 2 ? (unsigned short)0x3F80 : (unsigned short)0);
}

__device__ __forceinline__ f32x4 mfma16(bf16x8 a, bf16x8 b, f32x4 c) {
  return __builtin_amdgcn_mfma_f32_16x16x32_bf16(a, b, c, 0, 0, 0);
}

// ---------------- routing ----------------
__global__ __launch_bounds__(256) void route_kernel(
    const float* __restrict__ logits, int* __restrict__ counts,
    int* __restrict__ t2i, float* __restrict__ t2w) {
  const int t = blockIdx.x * 256 + threadIdx.x;
  if (t >= T_TOK) return;
  const float* l = logits + t * NEXP;
  float m0 = -1e30f, m1 = -1e30f;
  int i0 = 0, i1 = 0;
#pragma unroll
  for (int j = 0; j < NEXP; ++j) {
    const float v = l[j];
    if (v > m0) { m1 = m0; i1 = i0; m0 = v; i0 = j; }
    else if (v > m1) { m1 = v; i1 = j; }
  }
  const float w0 = 1.0f / (1.0f + expf(m1 - m0));  // renormalized top-2 softmax
  t2i[t] = i0 | (i1 << 8);
  t2w[t] = w0;
  atomicAdd(&counts[i0], 1);
  atomicAdd(&counts[i1], 1);
}

__global__ void scan_kernel(const int* __restrict__ counts,
                            int* __restrict__ offs, int* __restrict__ cursor) {
  if (threadIdx.x == 0) {
    int s = 0;
    for (int e = 0; e < NEXP; ++e) { offs[e] = s; cursor[e] = s; s += counts[e]; }
    offs[NEXP] = s;
  }
}

__global__ __launch_bounds__(256) void fill_kernel(
    const int* __restrict__ t2i, const float* __restrict__ t2w,
    int* __restrict__ cursor, int* __restrict__ pair_token,
    float* __restrict__ pair_wt, int* __restrict__ pair_eid,
    int* __restrict__ t2p0, int* __restrict__ t2p1) {
  const int t = blockIdx.x * 256 + threadIdx.x;
  if (t >= T_TOK) return;
  const int ii = t2i[t];
  const float w0 = t2w[t];
  const int i0 = ii & 255, i1 = (ii >> 8) & 255;
  const int p0 = atomicAdd(&cursor[i0], 1);
  pair_token[p0] = t; pair_wt[p0] = w0; pair_eid[p0] = i0;
  const int p1 = atomicAdd(&cursor[i1], 1);
  pair_token[p1] = t; pair_wt[p1] = 1.0f - w0; pair_eid[p1] = i1;
  t2p0[t] = p0; t2p1[t] = p1;
}

// ---------------- repack: int32-widened packed bytes -> dense u32 (4x less fetch) ----------------
__global__ __launch_bounds__(256) void repack_kernel(
    const int* __restrict__ w, u32* __restrict__ o) {
  // each thread: 4 consecutive u32 outputs (reads 4x int4 = 64 B, writes uint4 = 16 B)
  const int j0 = (blockIdx.x * 256 + threadIdx.x) * 4;
  const int4* w4 = (const int4*)w;
  uint4 r;
#pragma unroll
  for (int k = 0; k < 4; ++k) {
    const int4 a = w4[j0 + k];
    ((u32*)&r)[k] = (u32)(a.x & 255) | ((u32)(a.y & 255) << 8) |
                    ((u32)(a.z & 255) << 16) | ((u32)(a.w & 255) << 24);
  }
  ((uint4*)o)[blockIdx.x * 256 + threadIdx.x] = r;
}

// ---------------- xg prepass: xg[p,h] = bf16(x[tok(p),h] * a13[e(p),h]) ----------------
__global__ __launch_bounds__(256) void xg_kernel(
    const float* __restrict__ x, const int* __restrict__ a13q,
    const float* __restrict__ s13p, const int* __restrict__ pair_token,
    const int* __restrict__ pair_eid, unsigned short* __restrict__ xg) {
  const int p = blockIdx.x;
  const int t = pair_token[p];
  const int e = pair_eid[p];
  const float s13 = *s13p;
  const int h0 = threadIdx.x * 8;
  const float* xp = x + (size_t)t * HDIM + h0;
  const int* ap = a13q + (size_t)e * HDIM + h0;
  const float4 x0 = ((const float4*)xp)[0];
  const float4 x1 = ((const float4*)xp)[1];
  const int4 a0 = ((const int4*)ap)[0];
  const int4 a1 = ((const int4*)ap)[1];
  u16x8 q;
  q[0] = f2bf(x0.x * (float)a0.x * s13);
  q[1] = f2bf(x0.y * (float)a0.y * s13);
  q[2] = f2bf(x0.z * (float)a0.z * s13);
  q[3] = f2bf(x0.w * (float)a0.w * s13);
  q[4] = f2bf(x1.x * (float)a1.x * s13);
  q[5] = f2bf(x1.y * (float)a1.y * s13);
  q[6] = f2bf(x1.z * (float)a1.z * s13);
  q[7] = f2bf(x1.w * (float)a1.w * s13);
  *(u16x8*)(xg + (size_t)p * HDIM + h0) = q;
}

// ---------------- GEMM1: act'[pair,i] = silu(g)*u*a2 ----------------
// M=128 pairs x (64 gate + 64 up cols), K=2048, BK=32. A via global_load_lds,
// B from dense-packed u32 via LDS LUT. 3 blocks/CU resident (12 waves/CU).
__global__ __launch_bounds__(256, 3) void gemm1_kernel(
    const u32* __restrict__ wq13, const int* __restrict__ a2q,
    const float* __restrict__ s2p, const int* __restrict__ counts,
    const int* __restrict__ offs, const unsigned short* __restrict__ xg,
    unsigned short* __restrict__ act) {
  const int nT = blockIdx.x;  // 0..11
  const int mT = blockIdx.y;  // 0..31 (early exit)
  const int e  = blockIdx.z;
  const int cnt = counts[e];
  if (mT * 128 >= cnt) return;
  const int base = offs[e];
  const int tid = threadIdx.x;

  __shared__ unsigned short sA[128 * 32];  // unpadded: global_load_lds layout
  __shared__ unsigned short sB[128 * 40];  // pitch 40
  __shared__ uint2 lut[256];               // byte -> 4 bf16 ternary values

  {
    const int b = tid;
    const u32 lo = (u32)tb(b & 3) | ((u32)tb((b >> 2) & 3) << 16);
    const u32 hi = (u32)tb((b >> 4) & 3) | ((u32)tb((b >> 6) & 3) << 16);
    lut[b] = make_uint2(lo, hi);
  }
  __syncthreads();

  const int wave = tid >> 6, lane = tid & 63;
  const int quad = lane >> 4, ln = lane & 15;

  // B: 2 threads/row, one u32 (16 codes) each per kt
  const int bn = tid >> 1, bhalf = tid & 1;
  const int grow = (bn < 64) ? (nT * 64 + bn) : (IDIM + nT * 64 + (bn - 64));
  const u32* bptr = wq13 + ((size_t)e * (2 * IDIM) + grow) * (HDIM / 16) + bhalf;
  unsigned short* sBw = sB + bn * 40 + (bhalf << 4);

  const int arow = lane >> 2;
  const int acol = (lane & 3) * 8;
  const size_t arow0 = (size_t)(base + mT * 128);

  f32x4 acc[2][8] = {};

  for (int kt = 0; kt < HDIM / 32; ++kt) {
#pragma unroll
    for (int c = 0; c < 2; ++c) {
      const unsigned short* gp =
          xg + (arow0 + c * 64 + wave * 16 + arow) * HDIM + kt * 32 + acol;
      unsigned short* lp = sA + (c * 64 + wave * 16) * 32;  // wave-uniform base
      __builtin_amdgcn_global_load_lds((as1_u32p)(const void*)gp, (as3_u32p)(void*)lp, 16, 0, 0);
    }
    {
      const u32 wb = bptr[kt * 2];
      const uint2 q0 = lut[wb & 255], q1 = lut[(wb >> 8) & 255];
      const uint2 q2 = lut[(wb >> 16) & 255], q3 = lut[wb >> 24];
      *(uint2*)(sBw + 0) = q0;
      *(uint2*)(sBw + 4) = q1;
      *(uint2*)(sBw + 8) = q2;
      *(uint2*)(sBw + 12) = q3;
    }
    __syncthreads();
    bf16x8 af[2];
#pragma unroll
    for (int mi = 0; mi < 2; ++mi)
      af[mi] = *(const bf16x8*)(sA + (wave * 32 + mi * 16 + ln) * 32 + quad * 8);
#pragma unroll
    for (int ni = 0; ni < 8; ++ni) {
      const bf16x8 bf = *(const bf16x8*)(sB + (ni * 16 + ln) * 40 + quad * 8);
      acc[0][ni] = mfma16(af[0], bf, acc[0][ni]);
      acc[1][ni] = mfma16(af[1], bf, acc[1][ni]);
    }
    __syncthreads();
  }

  const float s2 = *s2p;
#pragma unroll
  for (int ni = 0; ni < 4; ++ni) {
    const int i = nT * 64 + ni * 16 + ln;
    const float a2v = (float)a2q[e * IDIM + i] * s2;
#pragma unroll
    for (int mi = 0; mi < 2; ++mi) {
      const f32x4 g = acc[mi][ni];
      const f32x4 u = acc[mi][ni + 4];
#pragma unroll
      for (int r = 0; r < 4; ++r) {
        const int m = mT * 128 + wave * 32 + mi * 16 + quad * 4 + r;
        if (m < cnt) {
          const float gv = g[r];
          const float av = gv / (1.0f + __expf(-gv)) * u[r];
          act[(size_t)(base + m) * IDIM + i] = f2bf(av * a2v);
        }
      }
    }
  }
}

// ---------------- GEMM2: down[pair,h] = act' . tern2 (or atomic out fallback) ----------------
template <bool ATOMIC>
__global__ __launch_bounds__(256, 3) void gemm2_kernel(
    const u32* __restrict__ wq2, const int* __restrict__ counts,
    const int* __restrict__ offs, const int* __restrict__ pair_token,
    const float* __restrict__ pair_wt, const unsigned short* __restrict__ act,
    float* __restrict__ dst) {  // ATOMIC ? out[t,h] : down[p,h]
  const int nT = blockIdx.x;  // 0..15
  const int mT = blockIdx.y;  // 0..31
  const int e  = blockIdx.z;
  const int cnt = counts[e];
  if (mT * 128 >= cnt) return;
  const int base = offs[e];
  const int tid = threadIdx.x;

  __shared__ unsigned short sA[128 * 32];
  __shared__ unsigned short sB[128 * 40];
  __shared__ uint2 lut[256];
  __shared__ int stok[128];
  __shared__ float swt[128];

  {
    const int b = tid;
    const u32 lo = (u32)tb(b & 3) | ((u32)tb((b >> 2) & 3) << 16);
    const u32 hi = (u32)tb((b >> 4) & 3) | ((u32)tb((b >> 6) & 3) << 16);
    lut[b] = make_uint2(lo, hi);
    if (ATOMIC && tid < 128) {
      const int m = mT * 128 + tid;
      const bool v = m < cnt;
      stok[tid] = v ? pair_token[base + m] : 0;
      swt[tid]  = v ? pair_wt[base + m] : 0.0f;
    }
  }
  __syncthreads();

  const int wave = tid >> 6, lane = tid & 63;
  const int quad = lane >> 4, ln = lane & 15;

  const int bn = tid >> 1, bhalf = tid & 1;
  const u32* bptr = wq2 + ((size_t)e * HDIM + nT * 128 + bn) * (IDIM / 16) + bhalf;
  unsigned short* sBw = sB + bn * 40 + (bhalf << 4);

  const int arow = lane >> 2;
  const int acol = (lane & 3) * 8;
  const size_t arow0 = (size_t)(base + mT * 128);

  f32x4 acc[2][8] = {};

  for (int kt = 0; kt < IDIM / 32; ++kt) {
#pragma unroll
    for (int c = 0; c < 2; ++c) {
      const unsigned short* gp =
          act + (arow0 + c * 64 + wave * 16 + arow) * IDIM + kt * 32 + acol;
      unsigned short* lp = sA + (c * 64 + wave * 16) * 32;
      __builtin_amdgcn_global_load_lds((as1_u32p)(const void*)gp, (as3_u32p)(void*)lp, 16, 0, 0);
    }
    {
      const u32 wb = bptr[kt * 2];
      const uint2 q0 = lut[wb & 255], q1 = lut[(wb >> 8) & 255];
      const uint2 q2 = lut[(wb >> 16) & 255], q3 = lut[wb >> 24];
      *(uint2*)(sBw + 0) = q0;
      *(uint2*)(sBw + 4) = q1;
      *(uint2*)(sBw + 8) = q2;
      *(uint2*)(sBw + 12) = q3;
    }
    __syncthreads();
    bf16x8 af[2];
#pragma unroll
    for (int mi = 0; mi < 2; ++mi)
      af[mi] = *(const bf16x8*)(sA + (wave * 32 + mi * 16 + ln) * 32 + quad * 8);
#pragma unroll
    for (int ni = 0; ni < 8; ++ni) {
      const bf16x8 bf = *(const bf16x8*)(sB + (ni * 16 + ln) * 40 + quad * 8);
      acc[0][ni] = mfma16(af[0], bf, acc[0][ni]);
      acc[1][ni] = mfma16(af[1], bf, acc[1][ni]);
    }
    __syncthreads();
  }

#pragma unroll
  for (int mi = 0; mi < 2; ++mi) {
#pragma unroll
    for (int r = 0; r < 4; ++r) {
      const int ml = wave * 32 + mi * 16 + quad * 4 + r;
      const int m = mT * 128 + ml;
      if (m < cnt) {
        if (ATOMIC) {
          const float wgt = swt[ml];
          float* orow = dst + (size_t)stok[ml] * HDIM + nT * 128;
#pragma unroll
          for (int ni = 0; ni < 8; ++ni)
            atomicAdd(orow + ni * 16 + ln, wgt * acc[mi][ni][r]);
        } else {
          float* drow = dst + (size_t)(base + m) * HDIM + nT * 128;
#pragma unroll
          for (int ni = 0; ni < 8; ++ni)
            drow[ni * 16 + ln] = acc[mi][ni][r];
        }
      }
    }
  }
}

// ---------------- combine: out[t,:] = w0*down[p0,:] + w1*down[p1,:] ----------------
__global__ __launch_bounds__(256) void combine_kernel(
    const int* __restrict__ t2p0, const int* __restrict__ t2p1,
    const float* __restrict__ t2w, const float* __restrict__ down,
    float* __restrict__ out) {
  const int t = blockIdx.x;
  const float w0 = t2w[t];
  const float w1 = 1.0f - w0;
  const float* d0 = down + (size_t)t2p0[t] * HDIM;
  const float* d1 = down + (size_t)t2p1[t] * HDIM;
  float* o = out + (size_t)t * HDIM;
  const int h = threadIdx.x * 8;
  const f32x4 a0 = *(const f32x4*)(d0 + h);
  const f32x4 a1 = *(const f32x4*)(d0 + h + 4);
  const f32x4 b0 = *(const f32x4*)(d1 + h);
  const f32x4 b1 = *(const f32x4*)(d1 + h + 4);
  *(f32x4*)(o + h) = w0 * a0 + w1 * b0;
  *(f32x4*)(o + h + 4) = w0 * a1 + w1 * b1;
}

// ================= Tier C fallback (round-2 kernels, widened-int B, M=256) =================
__global__ __launch_bounds__(256, 2) void gemm1_c(
    const int* __restrict__ w13p, const int* __restrict__ a2q,
    const float* __restrict__ s2p, const int* __restrict__ counts,
    const int* __restrict__ offs, const unsigned short* __restrict__ xg,
    unsigned short* __restrict__ act) {
  const int nT = blockIdx.x, mT = blockIdx.y, e = blockIdx.z;
  const int cnt = counts[e];
  if (mT * 256 >= cnt) return;
  const int base = offs[e];
  const int tid = threadIdx.x;
  __shared__ unsigned short sA[256 * 32];
  __shared__ unsigned short sB[128 * 40];
  __shared__ uint2 lut[256];
  {
    const int b = tid;
    const u32 lo = (u32)tb(b & 3) | ((u32)tb((b >> 2) & 3) << 16);
    const u32 hi = (u32)tb((b >> 4) & 3) | ((u32)tb((b >> 6) & 3) << 16);
    lut[b] = make_uint2(lo, hi);
  }
  __syncthreads();
  const int wave = tid >> 6, lane = tid & 63;
  const int quad = lane >> 4, ln = lane & 15;
  const int bn = tid >> 1, bhalf = tid & 1;
  const int grow = (bn < 64) ? (nT * 64 + bn) : (IDIM + nT * 64 + (bn - 64));
  const int* bptr = w13p + ((size_t)e * (2 * IDIM) + grow) * (HDIM / 4) + bhalf * 4;
  unsigned short* sBw = sB + bn * 40 + (bhalf << 4);
  const int arow = lane >> 2, acol = (lane & 3) * 8;
  const size_t arow0 = (size_t)(base + mT * 256);
  f32x4 acc[4][8] = {};
  for (int kt = 0; kt < HDIM / 32; ++kt) {
#pragma unroll
    for (int c = 0; c < 4; ++c) {
      const unsigned short* gp =
          xg + (arow0 + c * 64 + wave * 16 + arow) * HDIM + kt * 32 + acol;
      unsigned short* lp = sA + (c * 64 + wave * 16) * 32;
      __builtin_amdgcn_global_load_lds((as1_u32p)(const void*)gp, (as3_u32p)(void*)lp, 16, 0, 0);
    }
    {
      const int4 wv = *(const int4*)(bptr + kt * 8);
      const uint2 q0 = lut[wv.x], q1 = lut[wv.y], q2 = lut[wv.z], q3 = lut[wv.w];
      *(uint2*)(sBw + 0) = q0; *(uint2*)(sBw + 4) = q1;
      *(uint2*)(sBw + 8) = q2; *(uint2*)(sBw + 12) = q3;
    }
    __syncthreads();
    bf16x8 af[4];
#pragma unroll
    for (int mi = 0; mi < 4; ++mi)
      af[mi] = *(const bf16x8*)(sA + (wave * 64 + mi * 16 + ln) * 32 + quad * 8);
#pragma unroll
    for (int ni = 0; ni < 8; ++ni) {
      const bf16x8 bf = *(const bf16x8*)(sB + (ni * 16 + ln) * 40 + quad * 8);
#pragma unroll
      for (int mi = 0; mi < 4; ++mi) acc[mi][ni] = mfma16(af[mi], bf, acc[mi][ni]);
    }
    __syncthreads();
  }
  const float s2 = *s2p;
#pragma unroll
  for (int ni = 0; ni < 4; ++ni) {
    const int i = nT * 64 + ni * 16 + ln;
    const float a2v = (float)a2q[e * IDIM + i] * s2;
#pragma unroll
    for (int mi = 0; mi < 4; ++mi) {
      const f32x4 g = acc[mi][ni];
      const f32x4 u = acc[mi][ni + 4];
#pragma unroll
      for (int r = 0; r < 4; ++r) {
        const int m = mT * 256 + wave * 64 + mi * 16 + quad * 4 + r;
        if (m < cnt) {
          const float gv = g[r];
          const float av = gv / (1.0f + __expf(-gv)) * u[r];
          act[(size_t)(base + m) * IDIM + i] = f2bf(av * a2v);
        }
      }
    }
  }
}

__global__ __launch_bounds__(256, 2) void gemm2_c(
    const int* __restrict__ w2p, const int* __restrict__ counts,
    const int* __restrict__ offs, const int* __restrict__ pair_token,
    const float* __restrict__ pair_wt, const unsigned short* __restrict__ act,
    float* __restrict__ out) {
  const int nT = blockIdx.x, mT = blockIdx.y, e = blockIdx.z;
  const int cnt = counts[e];
  if (mT * 256 >= cnt) return;
  const int base = offs[e];
  const int tid = threadIdx.x;
  __shared__ unsigned short sA[256 * 32];
  __shared__ unsigned short sB[128 * 40];
  __shared__ uint2 lut[256];
  __shared__ int stok[256];
  __shared__ float swt[256];
  {
    const int b = tid;
    const u32 lo = (u32)tb(b & 3) | ((u32)tb((b >> 2) & 3) << 16);
    const u32 hi = (u32)tb((b >> 4) & 3) | ((u32)tb((b >> 6) & 3) << 16);
    lut[b] = make_uint2(lo, hi);
    const int m = mT * 256 + tid;
    const bool v = m < cnt;
    stok[tid] = v ? pair_token[base + m] : 0;
    swt[tid]  = v ? pair_wt[base + m] : 0.0f;
  }
  __syncthreads();
  const int wave = tid >> 6, lane = tid & 63;
  const int quad = lane >> 4, ln = lane & 15;
  const int bn = tid >> 1, bhalf = tid & 1;
  const int* bptr = w2p + ((size_t)e * HDIM + nT * 128 + bn) * (IDIM / 4) + bhalf * 4;
  unsigned short* sBw = sB + bn * 40 + (bhalf << 4);
  const int arow = lane >> 2, acol = (lane & 3) * 8;
  const size_t arow0 = (size_t)(base + mT * 256);
  f32x4 acc[4][8] = {};
  for (int kt = 0; kt < IDIM / 32; ++kt) {
#pragma unroll
    for (int c = 0; c < 4; ++c) {
      const unsigned short* gp =
          act + (arow0 + c * 64 + wave * 16 + arow) * IDIM + kt * 32 + acol;
      unsigned short* lp = sA + (c * 64 + wave * 16) * 32;
      __builtin_amdgcn_global_load_lds((as1_u32p)(const void*)gp, (as3_u32p)(void*)lp, 16, 0, 0);
    }
    {
      const int4 wv = *(const int4*)(bptr + kt * 8);
      const uint2 q0 = lut[wv.x], q1 = lut[wv.y], q2 = lut[wv.z], q3 = lut[wv.w];
      *(uint2*)(sBw + 0) = q0; *(uint2*)(sBw + 4) = q1;
      *(uint2*)(sBw + 8) = q2; *(uint2*)(sBw + 12) = q3;
    }
    __syncthreads();
    bf16x8 af[4];
#pragma unroll
    for (int mi = 0; mi < 4; ++mi)
      af[mi] = *(const bf16x8*)(sA + (wave * 64 + mi * 16 + ln) * 32 + quad * 8);
#pragma unroll
    for (int ni = 0; ni < 8; ++ni) {
      const bf16x8 bf = *(const bf16x8*)(sB + (ni * 16 + ln) * 40 + quad * 8);
#pragma unroll
      for (int mi = 0; mi < 4; ++mi) acc[mi][ni] = mfma16(af[mi], bf, acc[mi][ni]);
    }
    __syncthreads();
  }
#pragma unroll
  for (int mi = 0; mi < 4; ++mi) {
#pragma unroll
    for (int r = 0; r < 4; ++r) {
      const int ml = wave * 64 + mi * 16 + quad * 4 + r;
      const int m = mT * 256 + ml;
      if (m < cnt) {
        const float wgt = swt[ml];
        float* orow = out + (size_t)stok[ml] * HDIM + nT * 128;
#pragma unroll
        for (int ni = 0; ni < 8; ++ni)
          atomicAdd(orow + ni * 16 + ln, wgt * acc[mi][ni][r]);
      }
    }
  }
}

extern "C" void kernel_launch(void* const* d_in, const int* in_sizes, int n_in,
                              void* d_out, int out_size, void* d_ws, size_t ws_size,
                              hipStream_t stream) {
  const float* x      = (const float*)d_in[0];
  const float* logits = (const float*)d_in[1];
  const int*   w13p   = (const int*)d_in[2];   // harness widens uint8 -> int32
  const int*   a13q   = (const int*)d_in[3];
  const float* s13    = (const float*)d_in[4];
  const int*   w2p    = (const int*)d_in[5];
  const int*   a2q    = (const int*)d_in[6];
  const float* s2     = (const float*)d_in[7];
  float* out = (float*)d_out;

  char* ws = (char*)d_ws;
  int*   counts     = (int*)(ws + 0);
  int*   cursor     = (int*)(ws + 64);
  int*   offs       = (int*)(ws + 128);
  int*   t2i        = (int*)(ws + 256);
  float* t2w        = (float*)(ws + 256 + 4 * T_TOK);
  int*   t2p0       = (int*)(ws + 256 + 8 * T_TOK);
  int*   t2p1       = (int*)(ws + 256 + 12 * T_TOK);
  int*   pair_token = (int*)(ws + 256 + 16 * T_TOK);
  float* pair_wt    = (float*)(ws + 256 + 16 * T_TOK + 4 * PAIR_CAP);
  int*   pair_eid   = (int*)(ws + 256 + 16 * T_TOK + 8 * PAIR_CAP);
  const size_t hdr_end = ((size_t)(256 + 16 * T_TOK + 12 * PAIR_CAP) + 255) & ~(size_t)255;

  const size_t n32_13 = (size_t)NEXP * 2 * IDIM * (HDIM / 16);  // 3,145,728 u32
  const size_t n32_2  = (size_t)NEXP * HDIM * (IDIM / 16);      // 1,572,864 u32
  const size_t rp13_b = n32_13 * 4, rp2_b = n32_2 * 4;          // 12.6 + 6.3 MB
  const size_t xg_b   = (size_t)PAIR_CAP * HDIM * 2;            // 34.6 MB
  const size_t act_b  = (size_t)PAIR_CAP * IDIM * 2;            // 13.0 MB
  const size_t down_b = (size_t)PAIR_CAP * HDIM * 4;            // 69.2 MB

  const size_t need_A = hdr_end + rp13_b + rp2_b + xg_b + act_b + down_b;  // ~136 MB
  const size_t need_B = hdr_end + rp13_b + rp2_b + xg_b + act_b;           // ~67 MB
  // tier C: hdr_end + xg_b + act_b ~ 48 MB (known to fit from round 2)

  hipMemsetAsync(counts, 0, 256, stream);
  route_kernel<<<T_TOK / 256, 256, 0, stream>>>(logits, counts, t2i, t2w);
  scan_kernel<<<1, 64, 0, stream>>>(counts, offs, cursor);
  fill_kernel<<<T_TOK / 256, 256, 0, stream>>>(t2i, t2w, cursor, pair_token, pair_wt,
                                               pair_eid, t2p0, t2p1);

  if (ws_size >= need_B) {
    u32* rp13 = (u32*)(ws + hdr_end);
    u32* rp2  = (u32*)(ws + hdr_end + rp13_b);
    unsigned short* xg  = (unsigned short*)(ws + hdr_end + rp13_b + rp2_b);
    unsigned short* act = (unsigned short*)(ws + hdr_end + rp13_b + rp2_b + xg_b);
    repack_kernel<<<(int)(n32_13 / 1024), 256, 0, stream>>>(w13p, rp13);
    repack_kernel<<<(int)(n32_2 / 1024), 256, 0, stream>>>(w2p, rp2);
    xg_kernel<<<NPAIR, 256, 0, stream>>>(x, a13q, s13, pair_token, pair_eid, xg);
    gemm1_kernel<<<dim3(12, 32, 16), 256, 0, stream>>>(rp13, a2q, s2, counts, offs, xg, act);
    if (ws_size >= need_A) {
      float* down = (float*)(ws + need_B);
      gemm2_kernel<false><<<dim3(16, 32, 16), 256, 0, stream>>>(
          rp2, counts, offs, pair_token, pair_wt, act, down);
      combine_kernel<<<T_TOK, 256, 0, stream>>>(t2p0, t2p1, t2w, down, out);
    } else {
      hipMemsetAsync(out, 0, (size_t)out_size * sizeof(float), stream);
      gemm2_kernel<true><<<dim3(16, 32, 16), 256, 0, stream>>>(
          rp2, counts, offs, pair_token, pair_wt, act, out);
    }
  } else {
    unsigned short* xg  = (unsigned short*)(ws + hdr_end);
    unsigned short* act = (unsigned short*)(ws + hdr_end + xg_b);
    hipMemsetAsync(out, 0, (size_t)out_size * sizeof(float), stream);
    xg_kernel<<<NPAIR, 256, 0, stream>>>(x, a13q, s13, pair_token, pair_eid, xg);
    gemm1_c<<<dim3(12, 16, 16), 256, 0, stream>>>(w13p, a2q, s2, counts, offs, xg, act);
    gemm2_c<<<dim3(16, 16, 16), 256, 0, stream>>>(w2p, counts, offs, pair_token,
                                                  pair_wt, act, out);
  }
}

// Round 4
// 351.137 us; speedup vs baseline: 1.3388x; 1.1123x over previous
//
#include <hip/hip_runtime.h>
#include <stdint.h>

// Problem constants (reference: T=4096, H=2048, I=768, E=16, TOP_K=2)
#define T_TOK 4096
#define HDIM  2048
#define IDIM  768
#define NEXP  16
#define NPAIR (T_TOK * 2)        // 8192 (token, expert) pairs, exactly top-2
#define PAIR_CAP (NPAIR + 256)   // padded row bound for DMA reads past segment end

typedef float f32x4 __attribute__((ext_vector_type(4)));
typedef __bf16 bf16x8 __attribute__((ext_vector_type(8)));
typedef unsigned short u16x8 __attribute__((ext_vector_type(8)));
typedef unsigned int u32;
typedef const __attribute__((address_space(1))) u32* as1_u32p;
typedef __attribute__((address_space(3))) u32* as3_u32p;

__device__ __forceinline__ unsigned short f2bf(float f) {
  u32 u = __float_as_uint(f);
  u += 0x7FFFu + ((u >> 16) & 1u);
  return (unsigned short)(u >> 16);
}

__device__ __forceinline__ unsigned short tb(int m) {
  // 2-bit code m in {0,1,2} -> bf16 of {-1, 0, +1}
  return m == 0 ? (unsigned short)0xBF80 : (m == 2 ? (unsigned short)0x3F80 : (unsigned short)0);
}

__device__ __forceinline__ f32x4 mfma16(bf16x8 a, bf16x8 b, f32x4 c) {
  return __builtin_amdgcn_mfma_f32_16x16x32_bf16(a, b, c, 0, 0, 0);
}

// ---------------- routing ----------------
__global__ __launch_bounds__(256) void route_kernel(
    const float* __restrict__ logits, int* __restrict__ counts,
    int* __restrict__ t2i, float* __restrict__ t2w) {
  const int t = blockIdx.x * 256 + threadIdx.x;
  if (t >= T_TOK) return;
  const float* l = logits + t * NEXP;
  float m0 = -1e30f, m1 = -1e30f;
  int i0 = 0, i1 = 0;
#pragma unroll
  for (int j = 0; j < NEXP; ++j) {
    const float v = l[j];
    if (v > m0) { m1 = m0; i1 = i0; m0 = v; i0 = j; }
    else if (v > m1) { m1 = v; i1 = j; }
  }
  const float w0 = 1.0f / (1.0f + expf(m1 - m0));  // renormalized top-2 softmax
  t2i[t] = i0 | (i1 << 8);
  t2w[t] = w0;
  atomicAdd(&counts[i0], 1);
  atomicAdd(&counts[i1], 1);
}

__global__ void scan_kernel(const int* __restrict__ counts,
                            int* __restrict__ offs, int* __restrict__ cursor) {
  if (threadIdx.x == 0) {
    int s = 0;
    for (int e = 0; e < NEXP; ++e) { offs[e] = s; cursor[e] = s; s += counts[e]; }
    offs[NEXP] = s;
  }
}

__global__ __launch_bounds__(256) void fill_kernel(
    const int* __restrict__ t2i, const float* __restrict__ t2w,
    int* __restrict__ cursor, int* __restrict__ pair_token,
    float* __restrict__ pair_wt, int* __restrict__ pair_eid,
    int* __restrict__ t2p0, int* __restrict__ t2p1) {
  const int t = blockIdx.x * 256 + threadIdx.x;
  if (t >= T_TOK) return;
  const int ii = t2i[t];
  const float w0 = t2w[t];
  const int i0 = ii & 255, i1 = (ii >> 8) & 255;
  const int p0 = atomicAdd(&cursor[i0], 1);
  pair_token[p0] = t; pair_wt[p0] = w0; pair_eid[p0] = i0;
  const int p1 = atomicAdd(&cursor[i1], 1);
  pair_token[p1] = t; pair_wt[p1] = 1.0f - w0; pair_eid[p1] = i1;
  t2p0[t] = p0; t2p1[t] = p1;
}

// ---------------- repack: int32-widened packed bytes -> dense u32 ----------------
__global__ __launch_bounds__(256) void repack_kernel(
    const int* __restrict__ w, u32* __restrict__ o) {
  const int j0 = (blockIdx.x * 256 + threadIdx.x) * 4;
  const int4* w4 = (const int4*)w;
  uint4 r;
#pragma unroll
  for (int k = 0; k < 4; ++k) {
    const int4 a = w4[j0 + k];
    ((u32*)&r)[k] = (u32)(a.x & 255) | ((u32)(a.y & 255) << 8) |
                    ((u32)(a.z & 255) << 16) | ((u32)(a.w & 255) << 24);
  }
  ((uint4*)o)[blockIdx.x * 256 + threadIdx.x] = r;
}

// ---------------- xg prepass: xg[p,h] = bf16(x[tok(p),h] * a13[e(p),h]) ----------------
__global__ __launch_bounds__(256) void xg_kernel(
    const float* __restrict__ x, const int* __restrict__ a13q,
    const float* __restrict__ s13p, const int* __restrict__ pair_token,
    const int* __restrict__ pair_eid, unsigned short* __restrict__ xg) {
  const int p = blockIdx.x;
  const int t = pair_token[p];
  const int e = pair_eid[p];
  const float s13 = *s13p;
  const int h0 = threadIdx.x * 8;
  const float* xp = x + (size_t)t * HDIM + h0;
  const int* ap = a13q + (size_t)e * HDIM + h0;
  const float4 x0 = ((const float4*)xp)[0];
  const float4 x1 = ((const float4*)xp)[1];
  const int4 a0 = ((const int4*)ap)[0];
  const int4 a1 = ((const int4*)ap)[1];
  u16x8 q;
  q[0] = f2bf(x0.x * (float)a0.x * s13);
  q[1] = f2bf(x0.y * (float)a0.y * s13);
  q[2] = f2bf(x0.z * (float)a0.z * s13);
  q[3] = f2bf(x0.w * (float)a0.w * s13);
  q[4] = f2bf(x1.x * (float)a1.x * s13);
  q[5] = f2bf(x1.y * (float)a1.y * s13);
  q[6] = f2bf(x1.z * (float)a1.z * s13);
  q[7] = f2bf(x1.w * (float)a1.w * s13);
  *(u16x8*)(xg + (size_t)p * HDIM + h0) = q;
}

// ---------------- GEMM1: act'[pair,i] = wt * silu(g) * u * a2 ----------------
// Block 128 pairs x (64 gate + 64 up). Waves tiled 2x2, each 64 rows x 64 cols
// (gate ni 0..1 and up ni 2..3 in the same lane -> in-register silu fusion).
// XCD swizzle: all blocks of expert e land on XCD e%8 (id%8 round-robin).
__global__ __launch_bounds__(256, 4) void gemm1_kernel(
    const u32* __restrict__ wq13, const int* __restrict__ a2q,
    const float* __restrict__ s2p, const int* __restrict__ counts,
    const int* __restrict__ offs, const float* __restrict__ pair_wt,
    const unsigned short* __restrict__ xg, unsigned short* __restrict__ act) {
  const int id = blockIdx.x;
  const int xcd = id & 7, sblk = id >> 3;
  const int nT = sblk % 12;                 // 0..11 : i-range nT*64..+63
  const int gg = (sblk / 12) * 8 + xcd;     // 0..511 ; gg%8 == xcd
  const int e = gg & 15, mT = gg >> 4;      // e%8 == xcd -> per-expert XCD affinity
  const int cnt = counts[e];
  if (mT * 128 >= cnt) return;
  const int base = offs[e];
  const int tid = threadIdx.x;

  __shared__ unsigned short sA[128 * 32];      // unpadded (global_load_lds layout)
  __shared__ unsigned short sB[128 * 36 + 8];  // pitch 36: conflict-free frag reads
  __shared__ uint2 lut[256];                   // byte -> 4 bf16 ternary values

  {
    const int b = tid;
    const u32 lo = (u32)tb(b & 3) | ((u32)tb((b >> 2) & 3) << 16);
    const u32 hi = (u32)tb((b >> 4) & 3) | ((u32)tb((b >> 6) & 3) << 16);
    lut[b] = make_uint2(lo, hi);
  }
  __syncthreads();

  const int wave = tid >> 6, lane = tid & 63;
  const int wm = wave >> 1, wn = wave & 1;   // 2x2 wave grid
  const int quad = lane >> 4, ln = lane & 15;

  // B staging: 2 threads/row, 16 codes (one u32) each per kt
  const int bn = tid >> 1, bhalf = tid & 1;
  const int grow = (bn < 64) ? (nT * 64 + bn) : (IDIM + nT * 64 + (bn - 64));
  const u32* browp = wq13 + ((size_t)e * (2 * IDIM) + grow) * (HDIM / 16);
  unsigned short* sBw = sB + bn * 36 + (bhalf << 4);

  // A DMA: 2 instrs per wave, 16 rows x 32 cols each
  const int arow = lane >> 2;
  const int acol = (lane & 3) * 8;
  const size_t arow0 = (size_t)(base + mT * 128);

  f32x4 acc[4][4] = {};
  uint4 bq;

  for (int kt = 0; kt < HDIM / 32; ++kt) {
    if ((kt & 1) == 0) bq = *(const uint4*)(browp + kt * 2);  // 2 kt of B, aligned
#pragma unroll
    for (int c = 0; c < 2; ++c) {
      const unsigned short* gp =
          xg + (arow0 + wave * 32 + c * 16 + arow) * HDIM + kt * 32 + acol;
      unsigned short* lp = sA + (wave * 32 + c * 16) * 32;  // wave-uniform base
      __builtin_amdgcn_global_load_lds((as1_u32p)(const void*)gp, (as3_u32p)(void*)lp, 16, 0, 0);
    }
    {
      const u32 wb = (kt & 1) ? (bhalf ? bq.w : bq.z) : (bhalf ? bq.y : bq.x);
      const uint2 q0 = lut[wb & 255], q1 = lut[(wb >> 8) & 255];
      const uint2 q2 = lut[(wb >> 16) & 255], q3 = lut[wb >> 24];
      *(uint2*)(sBw + 0) = q0;
      *(uint2*)(sBw + 4) = q1;
      *(uint2*)(sBw + 8) = q2;
      *(uint2*)(sBw + 12) = q3;
    }
    __syncthreads();
    bf16x8 af[4], bf[4];
#pragma unroll
    for (int mi = 0; mi < 4; ++mi)
      af[mi] = *(const bf16x8*)(sA + (wm * 64 + mi * 16 + ln) * 32 + quad * 8);
#pragma unroll
    for (int ni = 0; ni < 4; ++ni) {
      const int brow = (ni < 2) ? (wn * 32 + ni * 16) : (64 + wn * 32 + (ni - 2) * 16);
      bf[ni] = *(const bf16x8*)(sB + (brow + ln) * 36 + quad * 8);
    }
#pragma unroll
    for (int ni = 0; ni < 4; ++ni)
#pragma unroll
      for (int mi = 0; mi < 4; ++mi) acc[mi][ni] = mfma16(af[mi], bf[ni], acc[mi][ni]);
    __syncthreads();
  }

  // epilogue: act' = bf16(wt * silu(gate) * up * a2[e,i])   (router weight folded in)
  const float s2 = *s2p;
#pragma unroll
  for (int gi = 0; gi < 2; ++gi) {
    const int i = nT * 64 + wn * 32 + gi * 16 + ln;
    const float a2v = (float)a2q[e * IDIM + i] * s2;
#pragma unroll
    for (int mi = 0; mi < 4; ++mi) {
      const f32x4 g = acc[mi][gi];
      const f32x4 u = acc[mi][gi + 2];
#pragma unroll
      for (int r = 0; r < 4; ++r) {
        const int m = mT * 128 + wm * 64 + mi * 16 + quad * 4 + r;
        if (m < cnt) {
          const float wt = pair_wt[base + m];
          const float gv = g[r];
          const float av = gv / (1.0f + __expf(-gv)) * u[r] * a2v * wt;
          act[(size_t)(base + m) * IDIM + i] = f2bf(av);
        }
      }
    }
  }
}

// ---------------- GEMM2: down[pair,h] (bf16) or atomic out[t,h] ----------------
// Block 128 pairs x 128 h. Waves 2x2 (64x64). act is pre-weighted.
template <bool ATOMIC>
__global__ __launch_bounds__(256, 4) void gemm2_kernel(
    const u32* __restrict__ wq2, const int* __restrict__ counts,
    const int* __restrict__ offs, const int* __restrict__ pair_token,
    const unsigned short* __restrict__ act, float* __restrict__ outp,
    unsigned short* __restrict__ down) {
  const int id = blockIdx.x;
  const int xcd = id & 7, sblk = id >> 3;
  const int nT = sblk & 15;                 // 0..15 : h-range nT*128..+127
  const int gg = (sblk >> 4) * 8 + xcd;
  const int e = gg & 15, mT = gg >> 4;
  const int cnt = counts[e];
  if (mT * 128 >= cnt) return;
  const int base = offs[e];
  const int tid = threadIdx.x;

  __shared__ unsigned short sA[128 * 32];
  __shared__ unsigned short sB[128 * 36 + 8];
  __shared__ uint2 lut[256];
  __shared__ int stok[128];

  {
    const int b = tid;
    const u32 lo = (u32)tb(b & 3) | ((u32)tb((b >> 2) & 3) << 16);
    const u32 hi = (u32)tb((b >> 4) & 3) | ((u32)tb((b >> 6) & 3) << 16);
    lut[b] = make_uint2(lo, hi);
    if (ATOMIC && tid < 128) {
      const int m = mT * 128 + tid;
      stok[tid] = (m < cnt) ? pair_token[base + m] : 0;
    }
  }
  __syncthreads();

  const int wave = tid >> 6, lane = tid & 63;
  const int wm = wave >> 1, wn = wave & 1;
  const int quad = lane >> 4, ln = lane & 15;

  const int bn = tid >> 1, bhalf = tid & 1;
  const u32* browp = wq2 + ((size_t)e * HDIM + nT * 128 + bn) * (IDIM / 16);
  unsigned short* sBw = sB + bn * 36 + (bhalf << 4);

  const int arow = lane >> 2;
  const int acol = (lane & 3) * 8;
  const size_t arow0 = (size_t)(base + mT * 128);

  f32x4 acc[4][4] = {};
  uint4 bq;

  for (int kt = 0; kt < IDIM / 32; ++kt) {
    if ((kt & 1) == 0) bq = *(const uint4*)(browp + kt * 2);
#pragma unroll
    for (int c = 0; c < 2; ++c) {
      const unsigned short* gp =
          act + (arow0 + wave * 32 + c * 16 + arow) * IDIM + kt * 32 + acol;
      unsigned short* lp = sA + (wave * 32 + c * 16) * 32;
      __builtin_amdgcn_global_load_lds((as1_u32p)(const void*)gp, (as3_u32p)(void*)lp, 16, 0, 0);
    }
    {
      const u32 wb = (kt & 1) ? (bhalf ? bq.w : bq.z) : (bhalf ? bq.y : bq.x);
      const uint2 q0 = lut[wb & 255], q1 = lut[(wb >> 8) & 255];
      const uint2 q2 = lut[(wb >> 16) & 255], q3 = lut[wb >> 24];
      *(uint2*)(sBw + 0) = q0;
      *(uint2*)(sBw + 4) = q1;
      *(uint2*)(sBw + 8) = q2;
      *(uint2*)(sBw + 12) = q3;
    }
    __syncthreads();
    bf16x8 af[4], bf[4];
#pragma unroll
    for (int mi = 0; mi < 4; ++mi)
      af[mi] = *(const bf16x8*)(sA + (wm * 64 + mi * 16 + ln) * 32 + quad * 8);
#pragma unroll
    for (int ni = 0; ni < 4; ++ni)
      bf[ni] = *(const bf16x8*)(sB + (wn * 64 + ni * 16 + ln) * 36 + quad * 8);
#pragma unroll
    for (int ni = 0; ni < 4; ++ni)
#pragma unroll
      for (int mi = 0; mi < 4; ++mi) acc[mi][ni] = mfma16(af[mi], bf[ni], acc[mi][ni]);
    __syncthreads();
  }

#pragma unroll
  for (int mi = 0; mi < 4; ++mi) {
#pragma unroll
    for (int r = 0; r < 4; ++r) {
      const int ml = wm * 64 + mi * 16 + quad * 4 + r;
      const int m = mT * 128 + ml;
      if (m < cnt) {
        const int col0 = nT * 128 + wn * 64;
        if (ATOMIC) {
          float* orow = outp + (size_t)stok[ml] * HDIM + col0;
#pragma unroll
          for (int ni = 0; ni < 4; ++ni)
            atomicAdd(orow + ni * 16 + ln, acc[mi][ni][r]);
        } else {
          unsigned short* drow = down + (size_t)(base + m) * HDIM + col0;
#pragma unroll
          for (int ni = 0; ni < 4; ++ni)
            drow[ni * 16 + ln] = f2bf(acc[mi][ni][r]);
        }
      }
    }
  }
}

// ---------------- combine: out[t,:] = down[p0,:] + down[p1,:]  (pre-weighted) ----------------
__global__ __launch_bounds__(256) void combine_kernel(
    const int* __restrict__ t2p0, const int* __restrict__ t2p1,
    const unsigned short* __restrict__ down, float* __restrict__ out) {
  const int t = blockIdx.x;
  const int h = threadIdx.x * 8;
  const u16x8 a = *(const u16x8*)(down + (size_t)t2p0[t] * HDIM + h);
  const u16x8 b = *(const u16x8*)(down + (size_t)t2p1[t] * HDIM + h);
  f32x4 o0, o1;
#pragma unroll
  for (int j = 0; j < 4; ++j) {
    o0[j] = __uint_as_float((u32)a[j] << 16) + __uint_as_float((u32)b[j] << 16);
    o1[j] = __uint_as_float((u32)a[j + 4] << 16) + __uint_as_float((u32)b[j + 4] << 16);
  }
  float* o = out + (size_t)t * HDIM + h;
  *(f32x4*)(o) = o0;
  *(f32x4*)(o + 4) = o1;
}

extern "C" void kernel_launch(void* const* d_in, const int* in_sizes, int n_in,
                              void* d_out, int out_size, void* d_ws, size_t ws_size,
                              hipStream_t stream) {
  const float* x      = (const float*)d_in[0];
  const float* logits = (const float*)d_in[1];
  const int*   w13p   = (const int*)d_in[2];   // harness widens uint8 -> int32
  const int*   a13q   = (const int*)d_in[3];
  const float* s13    = (const float*)d_in[4];
  const int*   w2p    = (const int*)d_in[5];
  const int*   a2q    = (const int*)d_in[6];
  const float* s2     = (const float*)d_in[7];
  float* out = (float*)d_out;

  char* ws = (char*)d_ws;
  int*   counts     = (int*)(ws + 0);
  int*   cursor     = (int*)(ws + 64);
  int*   offs       = (int*)(ws + 128);
  int*   t2i        = (int*)(ws + 256);
  float* t2w        = (float*)(ws + 256 + 4 * T_TOK);
  int*   t2p0       = (int*)(ws + 256 + 8 * T_TOK);
  int*   t2p1       = (int*)(ws + 256 + 12 * T_TOK);
  int*   pair_token = (int*)(ws + 256 + 16 * T_TOK);
  float* pair_wt    = (float*)(ws + 256 + 16 * T_TOK + 4 * PAIR_CAP);
  int*   pair_eid   = (int*)(ws + 256 + 16 * T_TOK + 8 * PAIR_CAP);
  const size_t hdr_end = ((size_t)(256 + 16 * T_TOK + 12 * PAIR_CAP) + 255) & ~(size_t)255;

  const size_t n32_13 = (size_t)NEXP * 2 * IDIM * (HDIM / 16);  // 3,145,728 u32
  const size_t n32_2  = (size_t)NEXP * HDIM * (IDIM / 16);      // 1,572,864 u32
  const size_t rp13_b = n32_13 * 4, rp2_b = n32_2 * 4;          // 12.6 + 6.3 MB
  const size_t xg_b   = (size_t)PAIR_CAP * HDIM * 2;            // 34.6 MB
  const size_t act_b  = (size_t)PAIR_CAP * IDIM * 2;            // 13.0 MB
  const size_t dwn_b  = (size_t)PAIR_CAP * HDIM * 2;            // 34.6 MB (bf16)

  const size_t need_B = hdr_end + rp13_b + rp2_b + xg_b + act_b;  // ~66.8 MB (proven fits)
  const size_t need_A = need_B + dwn_b;                           // ~101.4 MB

  u32* rp13 = (u32*)(ws + hdr_end);
  u32* rp2  = (u32*)(ws + hdr_end + rp13_b);
  unsigned short* xg  = (unsigned short*)(ws + hdr_end + rp13_b + rp2_b);
  unsigned short* act = (unsigned short*)(ws + hdr_end + rp13_b + rp2_b + xg_b);

  hipMemsetAsync(counts, 0, 256, stream);
  route_kernel<<<T_TOK / 256, 256, 0, stream>>>(logits, counts, t2i, t2w);
  scan_kernel<<<1, 64, 0, stream>>>(counts, offs, cursor);
  fill_kernel<<<T_TOK / 256, 256, 0, stream>>>(t2i, t2w, cursor, pair_token, pair_wt,
                                               pair_eid, t2p0, t2p1);
  repack_kernel<<<(int)(n32_13 / 1024), 256, 0, stream>>>(w13p, rp13);
  repack_kernel<<<(int)(n32_2 / 1024), 256, 0, stream>>>(w2p, rp2);
  xg_kernel<<<NPAIR, 256, 0, stream>>>(x, a13q, s13, pair_token, pair_eid, xg);

  // grid1: 64 (mT,e)-slots/XCD-group * 12 nT * 8 = 6144 ; all blocks of expert e on XCD e%8
  gemm1_kernel<<<6144, 256, 0, stream>>>(rp13, a2q, s2, counts, offs, pair_wt, xg, act);

  if (ws_size >= need_A) {
    unsigned short* down = (unsigned short*)(ws + need_B);
    gemm2_kernel<false><<<8192, 256, 0, stream>>>(rp2, counts, offs, pair_token,
                                                  act, nullptr, down);
    combine_kernel<<<T_TOK, 256, 0, stream>>>(t2p0, t2p1, down, out);
  } else {
    hipMemsetAsync(out, 0, (size_t)out_size * sizeof(float), stream);
    gemm2_kernel<true><<<8192, 256, 0, stream>>>(rp2, counts, offs, pair_token,
                                                 act, out, nullptr);
  }
}